// Round 2
// baseline (4812.481 us; speedup 1.0000x reference)
//
#include <hip/hip_runtime.h>
#include <cstdint>
#include <cmath>

// Problem constants (fixed by setup_inputs): z[4096,8,512] f32, emb[4096,512] f32
#define N_ROWS 32768
#define DIM    512
#define KCODES 4096
#define BM 64     // rows per block
#define BK 64     // codes per K-chunk
#define BD 64     // d per D-chunk
#define LDSP 68   // padded LDS stride (68*4B = 272B, multiple of 16 -> b128-aligned)
#define TAU 4e-3f // score-gap threshold below which we replicate numpy fp32 exactly

__device__ __forceinline__ bool lexGT(float v1, int i1, float v2, int i2) {
  // "better" = larger score; ties -> lower index (argmin keeps first min)
  return (v1 > v2) || (v1 == v2 && i1 < i2);
}

// numpy pairwise_sum (scalar path) of x[d]^2 over 512 contiguous floats.
// S512 = (B0+B1)+(B2+B3); each B = 128-elem base case: 8 accumulators
// r[j] = sum_{i≡j mod 8} x_i^2 (sequential), combined as
// ((r0+r1)+(r2+r3))+((r4+r5)+(r6+r7)).  fp contract OFF so x*x rounds
// separately from the add (numpy squares into a temp, then sums).
__device__ float np_sumsq_512(const float* __restrict__ a) {
#pragma clang fp contract(off)
  float B[4];
#pragma unroll
  for (int t = 0; t < 4; ++t) {
    const float* p = a + t * 128;
    float r[8];
#pragma unroll
    for (int j = 0; j < 8; ++j) { float x = p[j]; r[j] = x * x; }
    for (int i = 8; i < 128; i += 8) {
#pragma unroll
      for (int j = 0; j < 8; ++j) {
        float x = p[i + j];
        float sq = x * x;
        r[j] = r[j] + sq;
      }
    }
    B[t] = ((r[0] + r[1]) + (r[2] + r[3])) + ((r[4] + r[5]) + (r[6] + r[7]));
  }
  return (B[0] + B[1]) + (B[2] + B[3]);
}

// BLAS-sgemm-microkernel-style fp32 dot: one accumulator, sequential FMA
// over d = 0..511 (rank-1 update order of the GEBP kernel).
__device__ float np_dot_512(const float* __restrict__ x, const float* __restrict__ y) {
  float acc = 0.0f;
  for (int d = 0; d < DIM; ++d) acc = fmaf(x[d], y[d], acc);
  return acc;
}

// negHalf[k] = -0.5 * ||e_k||^2 (fp32, used only for the TAU-protected fast pass)
__global__ __launch_bounds__(256) void vq_prep(const float* __restrict__ emb,
                                               float* __restrict__ negHalf) {
  int k = blockIdx.x * 4 + (threadIdx.x >> 6);
  int lane = threadIdx.x & 63;
  const float4* e4 = (const float4*)(emb + (size_t)k * DIM);
  float4 a = e4[lane * 2];
  float4 b = e4[lane * 2 + 1];
  float s = a.x * a.x + a.y * a.y + a.z * a.z + a.w * a.w
          + b.x * b.x + b.y * b.y + b.z * b.z + b.w * b.w;
#pragma unroll
  for (int m = 1; m < 64; m <<= 1) s += __shfl_xor(s, m, 64);
  if (lane == 0) negHalf[k] = -0.5f * s;
}

__global__ __launch_bounds__(256) void vq_main(const float* __restrict__ z,
                                               const float* __restrict__ emb,
                                               const float* __restrict__ negHalf,
                                               float* __restrict__ out,
                                               float* __restrict__ blockSums) {
  __shared__ float Zs[BD * LDSP];  // transposed: Zs[d][row]
  __shared__ float Es[BD * LDSP];  // transposed: Es[d][code]
  __shared__ float wred[4];

  const int tid = threadIdx.x;
  const int tx = tid & 15;   // code dim (4 codes each)
  const int ty = tid >> 4;   // row dim  (4 rows each)
  const int m0 = blockIdx.x * BM;

  // per-thread running top-2 over this thread's own candidate set
  float R1[4], R2[4];
  int I1[4], I2[4];
#pragma unroll
  for (int i = 0; i < 4; ++i) {
    R1[i] = -INFINITY; R2[i] = -INFINITY;
    I1[i] = 0x7fffffff; I2[i] = 0x7fffffff;
  }

  for (int kc = 0; kc < KCODES; kc += BK) {
    float acc[4][4];
    float4 nh = *(const float4*)&negHalf[kc + tx * 4];
#pragma unroll
    for (int i = 0; i < 4; ++i) {
      acc[i][0] = nh.x; acc[i][1] = nh.y; acc[i][2] = nh.z; acc[i][3] = nh.w;
    }

    for (int dc = 0; dc < DIM; dc += BD) {
      __syncthreads();  // protect LDS from previous tile's readers
#pragma unroll
      for (int i = 0; i < 4; ++i) {
        int slot = tid + i * 256;
        int r  = slot >> 4;      // row (Z) / code (E) within tile
        int d4 = slot & 15;      // float4 index along d
        float4 zv = *(const float4*)&z[(size_t)(m0 + r) * DIM + dc + d4 * 4];
        float4 ev = *(const float4*)&emb[(size_t)(kc + r) * DIM + dc + d4 * 4];
        int db = d4 * 4;
        Zs[(db + 0) * LDSP + r] = zv.x;
        Zs[(db + 1) * LDSP + r] = zv.y;
        Zs[(db + 2) * LDSP + r] = zv.z;
        Zs[(db + 3) * LDSP + r] = zv.w;
        Es[(db + 0) * LDSP + r] = ev.x;
        Es[(db + 1) * LDSP + r] = ev.y;
        Es[(db + 2) * LDSP + r] = ev.z;
        Es[(db + 3) * LDSP + r] = ev.w;
      }
      __syncthreads();
#pragma unroll 8
      for (int dd = 0; dd < BD; ++dd) {
        float4 zv = *(const float4*)&Zs[dd * LDSP + ty * 4];
        float4 ev = *(const float4*)&Es[dd * LDSP + tx * 4];
        float zr[4] = {zv.x, zv.y, zv.z, zv.w};
        float er[4] = {ev.x, ev.y, ev.z, ev.w};
#pragma unroll
        for (int i = 0; i < 4; ++i)
#pragma unroll
          for (int j = 0; j < 4; ++j)
            acc[i][j] = fmaf(zr[i], er[j], acc[i][j]);
      }
    }

    // merge this chunk's 4 candidates per row into the per-thread top-2.
    // Candidates arrive in strictly increasing index, so '>' keeps the
    // earliest (lowest-index) on exact ties.
#pragma unroll
    for (int i = 0; i < 4; ++i) {
      int c0 = kc + tx * 4;
#pragma unroll
      for (int j = 0; j < 4; ++j) {
        float v = acc[i][j]; int c = c0 + j;
        if (v > R1[i]) { R2[i] = R1[i]; I2[i] = I1[i]; R1[i] = v; I1[i] = c; }
        else if (v > R2[i]) { R2[i] = v; I2[i] = c; }
      }
    }
  }

  // single final butterfly: merge the 16 per-thread top-2s (disjoint code
  // sets) into the per-row global top-2; all 16 lanes converge to identical
  // results (total order via lexGT).
#pragma unroll
  for (int m = 1; m < 16; m <<= 1) {
#pragma unroll
    for (int i = 0; i < 4; ++i) {
      float o1 = __shfl_xor(R1[i], m, 16);
      int   p1 = __shfl_xor(I1[i], m, 16);
      float o2 = __shfl_xor(R2[i], m, 16);
      int   p2 = __shfl_xor(I2[i], m, 16);
      if (lexGT(o1, p1, R1[i], I1[i])) {
        if (lexGT(R1[i], I1[i], o2, p2)) { R2[i] = R1[i]; I2[i] = I1[i]; }
        else { R2[i] = o2; I2[i] = p2; }
        R1[i] = o1; I1[i] = p1;
      } else {
        if (lexGT(o1, p1, R2[i], I2[i])) { R2[i] = o1; I2[i] = p1; }
      }
    }
  }

  // near-tie rows: replicate the numpy fp32 reference bit-for-bit on the two
  // candidates.  d_k = fl32( fl32(S + E_k) - 2*fl32(dot_k) ), argmin with
  // first-index tie-break.  All 16 lanes compute redundantly (same addresses,
  // broadcast loads) so the group stays converged with identical I1.
#pragma unroll
  for (int i = 0; i < 4; ++i) {
    if (R1[i] - R2[i] < TAU) {
#pragma clang fp contract(off)
      int row = m0 + ty * 4 + i;
      const float* zr = z + (size_t)row * DIM;
      const float* e1 = emb + (size_t)I1[i] * DIM;
      const float* e2 = emb + (size_t)I2[i] * DIM;
      float S  = np_sumsq_512(zr);
      float E1 = np_sumsq_512(e1);
      float E2 = np_sumsq_512(e2);
      float D1 = np_dot_512(zr, e1);
      float D2 = np_dot_512(zr, e2);
      float t1 = S + E1;
      float t2 = S + E2;
      float d1 = t1 - 2.0f * D1;  // 2*D exact (power-of-two scale)
      float d2 = t2 - 2.0f * D2;
      if (d2 < d1 || (d2 == d1 && I2[i] < I1[i])) I1[i] = I2[i];
    }
  }

  // epilogue: indices (as float), quantized_st (= e[best]), MSE partials
  float* outQ   = out + 1;
  float* outIdx = out + 1 + (size_t)N_ROWS * DIM;
  float lsum = 0.f;
#pragma unroll
  for (int i = 0; i < 4; ++i) {
    int row = m0 + ty * 4 + i;
    const float* zr = z + (size_t)row * DIM;
    const float* eb = emb + (size_t)I1[i] * DIM;
    float* oq = outQ + (size_t)row * DIM;
    if (tx == 0) outIdx[row] = (float)I1[i];
    for (int d = tx; d < DIM; d += 16) {
      float ev = eb[d];
      float df = ev - zr[d];
      oq[d] = ev;
      lsum = fmaf(df, df, lsum);
    }
  }
#pragma unroll
  for (int m = 1; m < 64; m <<= 1) lsum += __shfl_xor(lsum, m, 64);
  if ((tid & 63) == 0) wred[tid >> 6] = lsum;
  __syncthreads();
  if (tid == 0) blockSums[blockIdx.x] = wred[0] + wred[1] + wred[2] + wred[3];
}

// loss = (COMMITMENT 0.25 + QUANT 1.0) * mean((q - z)^2); KL factor is 0.
__global__ __launch_bounds__(256) void vq_final(const float* __restrict__ blockSums,
                                                float* __restrict__ out) {
  __shared__ float red[256];
  int t = threadIdx.x;
  red[t] = blockSums[t] + blockSums[t + 256];
  __syncthreads();
  for (int s = 128; s > 0; s >>= 1) {
    if (t < s) red[t] += red[t + s];
    __syncthreads();
  }
  if (t == 0) out[0] = red[0] * (1.25f / 16777216.0f);
}

extern "C" void kernel_launch(void* const* d_in, const int* in_sizes, int n_in,
                              void* d_out, int out_size, void* d_ws, size_t ws_size,
                              hipStream_t stream) {
  const float* z   = (const float*)d_in[0];
  const float* emb = (const float*)d_in[1];
  float* out = (float*)d_out;
  float* negHalf   = (float*)d_ws;          // 4096 floats
  float* blockSums = negHalf + KCODES;      // 512 floats
  (void)in_sizes; (void)n_in; (void)out_size; (void)ws_size;

  vq_prep<<<KCODES / 4, 256, 0, stream>>>(emb, negHalf);
  vq_main<<<N_ROWS / BM, 256, 0, stream>>>(z, emb, negHalf, out, blockSums);
  vq_final<<<1, 256, 0, stream>>>(blockSums, out);
}

// Round 3
// 568.641 us; speedup vs baseline: 8.4631x; 8.4631x over previous
//
#include <hip/hip_runtime.h>
#include <cstdint>
#include <cmath>

// Problem constants: z[4096,8,512] f32, emb[4096,512] f32
#define N_ROWS 32768
#define DIM    512
#define KCODES 4096
#define BM 128      // rows per block (8 waves x 16 rows)
#define BN 64       // codes per K-chunk
#define DC 128      // d elements per LDS tile
#define NKC (KCODES / BN)   // 64 code chunks
#define TAU 2e-3f   // score-gap threshold for np-exact refinement (~20 sigma)

typedef _Float16 f16x8 __attribute__((ext_vector_type(8)));
typedef float    f32x4 __attribute__((ext_vector_type(4)));

__device__ __forceinline__ bool lexGT(float v1, int i1, float v2, int i2) {
  return (v1 > v2) || (v1 == v2 && i1 < i2);
}

// ---- numpy fp32 bit-exact helpers (verified passing in round 2) ----
__device__ float np_sumsq_512(const float* __restrict__ a) {
#pragma clang fp contract(off)
  float B[4];
#pragma unroll
  for (int t = 0; t < 4; ++t) {
    const float* p = a + t * 128;
    float r[8];
#pragma unroll
    for (int j = 0; j < 8; ++j) { float x = p[j]; r[j] = x * x; }
    for (int i = 8; i < 128; i += 8) {
#pragma unroll
      for (int j = 0; j < 8; ++j) {
        float x = p[i + j];
        float sq = x * x;
        r[j] = r[j] + sq;
      }
    }
    B[t] = ((r[0] + r[1]) + (r[2] + r[3])) + ((r[4] + r[5]) + (r[6] + r[7]));
  }
  return (B[0] + B[1]) + (B[2] + B[3]);
}

__device__ float np_dot_512(const float* __restrict__ x, const float* __restrict__ y) {
  float acc = 0.0f;
  for (int d = 0; d < DIM; ++d) acc = fmaf(x[d], y[d], acc);
  return acc;
}

// negHalf[k] = -0.5 * ||e_k||^2 (exact fp32 input; used only in the fast pass)
__global__ __launch_bounds__(256) void vq_prep(const float* __restrict__ emb,
                                               float* __restrict__ negHalf) {
  int k = blockIdx.x * 4 + (threadIdx.x >> 6);
  int lane = threadIdx.x & 63;
  const float4* e4 = (const float4*)(emb + (size_t)k * DIM);
  float4 a = e4[lane * 2];
  float4 b = e4[lane * 2 + 1];
  float s = a.x * a.x + a.y * a.y + a.z * a.z + a.w * a.w
          + b.x * b.x + b.y * b.y + b.z * b.z + b.w * b.w;
#pragma unroll
  for (int m = 1; m < 64; m <<= 1) s += __shfl_xor(s, m, 64);
  if (lane == 0) negHalf[k] = -0.5f * s;
}

__global__ __launch_bounds__(512, 2) void vq_main(const float* __restrict__ z,
                                                  const float* __restrict__ emb,
                                                  const float* __restrict__ negHalf,
                                                  float* __restrict__ out,
                                                  float* __restrict__ blockSums) {
  // double-buffered E tile: [buf][64 codes][16 slots of 8 f16], XOR-swizzled slots
  __shared__ f16x8 EHs[2 * 64 * 16];   // 32 KiB
  __shared__ int   idxbuf[BM];
  __shared__ float wred[8];

  const int tid  = threadIdx.x;
  const int w    = tid >> 6;        // wave 0..7
  const int lane = tid & 63;
  const int tl   = lane & 15;       // intra-16 lane
  const int gh   = lane >> 4;       // k-group 0..3
  const int m0   = blockIdx.x * BM;
  const int zrow = m0 + w * 16 + tl;   // A-fragment row for this lane

  // ---- load this wave's 16 z-rows as resident f16 hi/lo fragments ----
  // A-frag layout for mfma_f32_16x16x32: lane holds row=(lane&15), k=(lane>>4)*8+j
  f16x8 zh[16], zl[16];
  {
    const float* zp = z + (size_t)zrow * DIM + gh * 8;
#pragma unroll
    for (int c = 0; c < 16; ++c) {
      float4 a = *(const float4*)(zp + c * 32);
      float4 b = *(const float4*)(zp + c * 32 + 4);
      float f[8] = {a.x, a.y, a.z, a.w, b.x, b.y, b.z, b.w};
      f16x8 h, lo;
#pragma unroll
      for (int j = 0; j < 8; ++j) {
        _Float16 hv = (_Float16)f[j];
        h[j]  = hv;
        lo[j] = (_Float16)(f[j] - (float)hv);  // exact residual (Sterbenz), then RNE
      }
      zh[c] = h; zl[c] = lo;
    }
  }

  // per-thread running top-3 for 4 rows (C/D rows gh*4+0..3)
  float R1[4], R2[4], R3[4];
  int   I1[4], I2[4], I3[4];
#pragma unroll
  for (int i = 0; i < 4; ++i) {
    R1[i] = -INFINITY; R2[i] = -INFINITY; R3[i] = -INFINITY;
    I1[i] = 0x7fffffff; I2[i] = 0x7fffffff; I3[i] = 0x7fffffff;
  }

  // ---- staging helper (expressed inline): tile (k0, dc) -> EHs[buf] ----
  // thread t handles segments t and t+512; seg: row=seg>>4, slot=seg&15.
#define STAGE(k0_, dc_, buf_)                                                   \
  {                                                                             \
    _Pragma("unroll")                                                           \
    for (int p = 0; p < 2; ++p) {                                               \
      int seg = tid + p * 512;                                                  \
      int r = seg >> 4, s = seg & 15;                                           \
      const float* ep = emb + (size_t)((k0_) + r) * DIM + (dc_) + s * 8;        \
      float4 a = *(const float4*)ep;                                            \
      float4 b = *(const float4*)(ep + 4);                                      \
      float f[8] = {a.x, a.y, a.z, a.w, b.x, b.y, b.z, b.w};                    \
      f16x8 h;                                                                  \
      _Pragma("unroll")                                                         \
      for (int j = 0; j < 8; ++j) h[j] = (_Float16)f[j];                        \
      EHs[(buf_) * 1024 + r * 16 + (s ^ (r & 7))] = h;                          \
    }                                                                           \
  }

  // prologue: stage tile (kc=0, dc=0) into buf 0
  STAGE(0, 0, 0);
  __syncthreads();

  for (int kc = 0; kc < NKC; ++kc) {
    const int k0 = kc * BN;
    // init acc with -0.5||e||^2 (exact), broadcast across the 4 row-regs
    f32x4 acc[4];
#pragma unroll
    for (int ct = 0; ct < 4; ++ct) {
      float nh = negHalf[k0 + ct * 16 + tl];
      acc[ct] = (f32x4){nh, nh, nh, nh};
    }

#pragma unroll
    for (int dci = 0; dci < 4; ++dci) {
      const int cur = dci & 1;
      const int nxt = cur ^ 1;
      const bool has_next = !(kc == NKC - 1 && dci == 3);
      const int nkc = (dci == 3) ? (kc + 1) : kc;
      const int ndc = ((dci + 1) & 3) * DC;

      // issue next tile's staging (global loads hoist above the MFMAs)
      if (has_next) STAGE(nkc * BN, ndc, nxt);

      // compute current tile: 4 K-steps of 32, 4 code-subtiles
#pragma unroll
      for (int ks = 0; ks < 4; ++ks) {
        f16x8 bf[4];
#pragma unroll
        for (int ct = 0; ct < 4; ++ct)
          bf[ct] = EHs[cur * 1024 + (ct * 16 + tl) * 16 + ((ks * 4 + gh) ^ (tl & 7))];
#pragma unroll
        for (int ct = 0; ct < 4; ++ct) {
          acc[ct] = __builtin_amdgcn_mfma_f32_16x16x32_f16(zh[dci * 4 + ks], bf[ct], acc[ct], 0, 0, 0);
          acc[ct] = __builtin_amdgcn_mfma_f32_16x16x32_f16(zl[dci * 4 + ks], bf[ct], acc[ct], 0, 0, 0);
        }
      }
      __syncthreads();
    }

    // merge 16 candidates (4 codes x 4 rows) into running top-3
#pragma unroll
    for (int ct = 0; ct < 4; ++ct) {
      int c = k0 + ct * 16 + tl;
#pragma unroll
      for (int r = 0; r < 4; ++r) {
        float v = acc[ct][r];
        if (v > R3[r]) {
          if (v > R1[r]) {
            R3[r] = R2[r]; I3[r] = I2[r];
            R2[r] = R1[r]; I2[r] = I1[r];
            R1[r] = v;     I1[r] = c;
          } else if (v > R2[r]) {
            R3[r] = R2[r]; I3[r] = I2[r];
            R2[r] = v;     I2[r] = c;
          } else {
            R3[r] = v;     I3[r] = c;
          }
        }
      }
    }
  }

  // ---- butterfly top-3 merge across the 16 lanes of each row-group ----
#pragma unroll
  for (int m = 1; m < 16; m <<= 1) {
#pragma unroll
    for (int i = 0; i < 4; ++i) {
      float b1 = __shfl_xor(R1[i], m); int j1 = __shfl_xor(I1[i], m);
      float b2 = __shfl_xor(R2[i], m); int j2 = __shfl_xor(I2[i], m);
      float b3 = __shfl_xor(R3[i], m); int j3 = __shfl_xor(I3[i], m);
#pragma unroll
      for (int q = 0; q < 3; ++q) {
        float v = (q == 0) ? b1 : (q == 1) ? b2 : b3;
        int   c = (q == 0) ? j1 : (q == 1) ? j2 : j3;
        if (lexGT(v, c, R3[i], I3[i])) {
          if (lexGT(v, c, R1[i], I1[i])) {
            R3[i] = R2[i]; I3[i] = I2[i];
            R2[i] = R1[i]; I2[i] = I1[i];
            R1[i] = v;     I1[i] = c;
          } else if (lexGT(v, c, R2[i], I2[i])) {
            R3[i] = R2[i]; I3[i] = I2[i];
            R2[i] = v;     I2[i] = c;
          } else {
            R3[i] = v;     I3[i] = c;
          }
        }
      }
    }
  }

  // ---- near-tie rows: replicate numpy fp32 bit-exact on 2-3 candidates ----
#pragma unroll
  for (int i = 0; i < 4; ++i) {
    if (R1[i] - R2[i] < TAU) {
#pragma clang fp contract(off)
      int row = m0 + w * 16 + gh * 4 + i;
      const float* zr = z + (size_t)row * DIM;
      float S = np_sumsq_512(zr);
      const float* e1 = emb + (size_t)I1[i] * DIM;
      const float* e2 = emb + (size_t)I2[i] * DIM;
      float E1 = np_sumsq_512(e1), E2 = np_sumsq_512(e2);
      float D1 = np_dot_512(zr, e1), D2 = np_dot_512(zr, e2);
      float t1 = S + E1, t2 = S + E2;
      float d1 = t1 - 2.0f * D1;
      float d2 = t2 - 2.0f * D2;
      float dbest = d1; int ibest = I1[i];
      if (d2 < dbest || (d2 == dbest && I2[i] < ibest)) { dbest = d2; ibest = I2[i]; }
      if (R1[i] - R3[i] < TAU) {
        const float* e3 = emb + (size_t)I3[i] * DIM;
        float E3 = np_sumsq_512(e3);
        float D3 = np_dot_512(zr, e3);
        float t3 = S + E3;
        float d3 = t3 - 2.0f * D3;
        if (d3 < dbest || (d3 == dbest && I3[i] < ibest)) { dbest = d3; ibest = I3[i]; }
      }
      I1[i] = ibest;
    }
  }

  // publish per-row best index
  float* outQ   = out + 1;
  float* outIdx = out + 1 + (size_t)N_ROWS * DIM;
  if (tl == 0) {
#pragma unroll
    for (int i = 0; i < 4; ++i) {
      int rl = w * 16 + gh * 4 + i;
      idxbuf[rl] = I1[i];
      outIdx[m0 + rl] = (float)I1[i];
    }
  }
  __syncthreads();

  // ---- epilogue: gather e[best] (exact), write quantized, loss partial ----
  float lsum = 0.f;
  {
    int fr = w * 16 + tl;                       // this lane's fragment row
    int bestk = idxbuf[fr];
    const float* ep = emb + (size_t)bestk * DIM + gh * 8;
    float* oq = outQ + (size_t)(m0 + fr) * DIM + gh * 8;
#pragma unroll
    for (int c = 0; c < 16; ++c) {
      float4 a = *(const float4*)(ep + c * 32);
      float4 b = *(const float4*)(ep + c * 32 + 4);
      float e8[8] = {a.x, a.y, a.z, a.w, b.x, b.y, b.z, b.w};
      f16x8 h = zh[c], lo = zl[c];
#pragma unroll
      for (int j = 0; j < 8; ++j) {
        float zr = (float)h[j] + (float)lo[j];  // z to 2^-22 — plenty for loss
        float df = e8[j] - zr;
        lsum = fmaf(df, df, lsum);
        oq[c * 32 + j] = e8[j];                 // scalar: outQ is 4B-aligned only
      }
    }
  }
#pragma unroll
  for (int m = 1; m < 64; m <<= 1) lsum += __shfl_xor(lsum, m, 64);
  if (lane == 0) wred[w] = lsum;
  __syncthreads();
  if (tid == 0) {
    float s = 0.f;
#pragma unroll
    for (int q = 0; q < 8; ++q) s += wred[q];
    blockSums[blockIdx.x] = s;
  }
#undef STAGE
}

// loss = (0.25 + 1.0) * mean((q - z)^2); KL factor is 0. 256 block sums.
__global__ __launch_bounds__(256) void vq_final(const float* __restrict__ blockSums,
                                                float* __restrict__ out) {
  __shared__ float red[256];
  int t = threadIdx.x;
  red[t] = blockSums[t];
  __syncthreads();
  for (int s = 128; s > 0; s >>= 1) {
    if (t < s) red[t] += red[t + s];
    __syncthreads();
  }
  if (t == 0) out[0] = red[0] * (1.25f / 16777216.0f);
}

extern "C" void kernel_launch(void* const* d_in, const int* in_sizes, int n_in,
                              void* d_out, int out_size, void* d_ws, size_t ws_size,
                              hipStream_t stream) {
  const float* z   = (const float*)d_in[0];
  const float* emb = (const float*)d_in[1];
  float* out = (float*)d_out;
  float* negHalf   = (float*)d_ws;          // 4096 floats
  float* blockSums = negHalf + KCODES;      // 256 floats
  (void)in_sizes; (void)n_in; (void)out_size; (void)ws_size;

  vq_prep<<<KCODES / 4, 256, 0, stream>>>(emb, negHalf);
  vq_main<<<N_ROWS / BM, 512, 0, stream>>>(z, emb, negHalf, out, blockSums);
  vq_final<<<1, 256, 0, stream>>>(blockSums, out);
}